// Round 5
// baseline (381.856 us; speedup 1.0000x reference)
//
#include <hip/hip_runtime.h>
#include <stdint.h>

#define NH 8
#define HD 48
#define CC 384
#define NN 4096
#define CK 384

typedef short short8 __attribute__((ext_vector_type(8)));
typedef float floatx4 __attribute__((ext_vector_type(4)));

__device__ inline unsigned short f32_to_bf16_bits(float f) {
    uint32_t u = __builtin_bit_cast(uint32_t, f);
    u = (u + 0x7FFFu + ((u >> 16) & 1u)) >> 16;
    return (unsigned short)u;
}
__device__ inline short8 load8(const unsigned short* p) {
    return *reinterpret_cast<const short8*>(p);
}
typedef __attribute__((address_space(1))) const void gvoid_t;
typedef __attribute__((address_space(3))) void lvoid_t;
__device__ inline void async16(const unsigned short* g, unsigned short* l) {
    __builtin_amdgcn_global_load_lds((gvoid_t*)g, (lvoid_t*)l, 16, 0, 0);
}

// ---------------- weight convert f32 -> bf16 ----------------
__global__ __launch_bounds__(256) void k_cvt(
    const float* __restrict__ src, unsigned short* __restrict__ dst, int n8)
{
    int i = blockIdx.x * 256 + threadIdx.x;
    if (i >= n8) return;
    const float* s = src + (size_t)i * 8;
    unsigned short t[8];
    #pragma unroll
    for (int j = 0; j < 8; ++j) t[j] = f32_to_bf16_bits(s[j]);
    *reinterpret_cast<short8*>(dst + (size_t)i * 8) = *reinterpret_cast<short8*>(t);
}

// ---------------- x transpose: [B][C][N] f32 -> [B*N][C] bf16 ----------------
__global__ __launch_bounds__(256) void k_tr(
    const float* __restrict__ x, unsigned short* __restrict__ xT)
{
    __shared__ unsigned short tile[64][72];
    int bx = blockIdx.x;
    int nt = bx & 63; int rest = bx >> 6; int ct = rest % 6; int b = rest / 6;
    int c0 = ct * 64, n0 = nt * 64;
    int t = threadIdx.x;
    int nl = t & 63, w = t >> 6;
    const float* xb = x + (size_t)b * CC * NN;
    #pragma unroll
    for (int i = 0; i < 4; ++i) {
        int cl = w * 16 + i * 4;
        unsigned short u[4];
        #pragma unroll
        for (int j = 0; j < 4; ++j)
            u[j] = f32_to_bf16_bits(xb[(size_t)(c0 + cl + j) * NN + n0 + nl]);
        *reinterpret_cast<uint2*>(&tile[nl][cl]) = *reinterpret_cast<uint2*>(u);
    }
    __syncthreads();
    #pragma unroll
    for (int it = 0; it < 2; ++it) {
        int v = it * 256 + t;
        int row = v >> 3, seg = v & 7;
        *reinterpret_cast<short8*>(xT + ((size_t)b * NN + n0 + row) * CK + c0 + seg * 8) =
            load8(&tile[row][seg * 8]);
    }
}

// ---------------- QKV GEMM (128x128, BK=32 double-buffered, seg-XOR swizzle) ----------------
// A = xT [65536][384], W = w1 [1152][384]; out: QK [tok][768] + Vt [B][8][48][4096]
// BK=32: staging = 2 x 16 KiB -> with 34.8 KB arena total, 4 blocks/CU (was 2 at BK=64).
// Swizzle (rule #21 both-sides): LDS chunk c holds global seg (c&3)^(row&3); linear LDS
// dest for global_load_lds, inverse-permuted global src, XOR on ds_read. 16-way -> 4-way.
__global__ __launch_bounds__(256) void k_qkv(
    const unsigned short* __restrict__ A,
    const unsigned short* __restrict__ W,
    unsigned short* __restrict__ QK,
    unsigned short* __restrict__ Vt)
{
    __shared__ unsigned short smem[17408];   // 16384 staging (2 buf x 8192) + epilogue arena
    // XCD-aware swizzle (T1): 4608 blocks = 8 XCDs x 576 (bijective).
    int bx = blockIdx.x;
    int l  = (bx & 7) * 576 + (bx >> 3);
    int tf = l % 9, tm = l / 9;
    int m0 = tm * 128, f0 = tf * 128;
    int tid = threadIdx.x, wid = tid >> 6, lane = tid & 63;
    int l15 = lane & 15, quad = lane >> 4;
    int wm = wid & 1, wn = wid >> 1;

    const unsigned short* Ab = A + (size_t)m0 * CK;
    const unsigned short* Wb = W + (size_t)f0 * CK;

    floatx4 acc[4][4] = {};

    // stage one 32-K tile pair into buffer `buf` (issue only; drained by __syncthreads)
    auto stage = [&](int kt, int buf) {
        int k0 = kt * 32;
        unsigned short* Asd = smem + buf * 8192;
        unsigned short* Wsd = Asd + 4096;
        #pragma unroll
        for (int i = 0; i < 2; ++i) {
            int c = i * 256 + tid;
            int row = c >> 2;
            int sg  = (c & 3) ^ (row & 3);   // inverse-permuted global seg
            async16(Ab + (size_t)row * CK + k0 + sg * 8, Asd + (i * 256 + wid * 64) * 8);
            async16(Wb + (size_t)row * CK + k0 + sg * 8, Wsd + (i * 256 + wid * 64) * 8);
        }
    };

    stage(0, 0);
    __syncthreads();

    int sx = (quad ^ (l15 & 3)) * 8;         // swizzled ds_read seg offset (shorts)
    int cur = 0;
    #pragma unroll
    for (int kk = 0; kk < 12; ++kk) {
        if (kk < 11) stage(kk + 1, cur ^ 1); // prefetch next tile; in flight under MFMA
        unsigned short* As = smem + cur * 8192;
        unsigned short* Ws = As + 4096;
        short8 a[4], bf[4];
        #pragma unroll
        for (int i = 0; i < 4; ++i)
            a[i] = load8(As + (wm * 64 + i * 16 + l15) * 32 + sx);
        #pragma unroll
        for (int j = 0; j < 4; ++j)
            bf[j] = load8(Ws + (wn * 64 + j * 16 + l15) * 32 + sx);
        #pragma unroll
        for (int i = 0; i < 4; ++i)
            #pragma unroll
            for (int j = 0; j < 4; ++j)
                acc[i][j] = __builtin_amdgcn_mfma_f32_16x16x32_bf16(a[i], bf[j], acc[i][j], 0, 0, 0);
        __syncthreads();                     // drains prefetch (vmcnt 0) + barrier
        cur ^= 1;
    }

    int b = m0 >> 12, nb = m0 & 4095;
    if (tf < 6) {
        #pragma unroll
        for (int i = 0; i < 4; ++i)
            #pragma unroll
            for (int j = 0; j < 4; ++j)
                #pragma unroll
                for (int r = 0; r < 4; ++r)
                    smem[(wm * 64 + i * 16 + quad * 4 + r) * 128 + wn * 64 + j * 16 + l15] =
                        f32_to_bf16_bits(acc[i][j][r]);
        __syncthreads();
        #pragma unroll
        for (int it = 0; it < 8; ++it) {
            int c = it * 256 + tid;
            int row = c >> 4, seg = c & 15;
            *reinterpret_cast<short8*>(QK + (size_t)(m0 + row) * 768 + f0 + seg * 8) =
                load8(smem + row * 128 + seg * 8);
        }
    } else {
        #pragma unroll
        for (int i = 0; i < 4; ++i)
            #pragma unroll
            for (int j = 0; j < 4; ++j)
                #pragma unroll
                for (int r = 0; r < 4; ++r)
                    smem[(wn * 64 + j * 16 + l15) * 136 + wm * 64 + i * 16 + quad * 4 + r] =
                        f32_to_bf16_bits(acc[i][j][r]);
        __syncthreads();
        int fvb = (tf - 6) * 128;
        #pragma unroll
        for (int it = 0; it < 8; ++it) {
            int c = it * 256 + tid;
            int fl = c >> 4, seg = c & 15;
            int fv = fvb + fl;
            int h = fv / 48, d = fv - h * 48;
            *reinterpret_cast<short8*>(Vt + (((size_t)(b * 8 + h) * 48 + d) << 12) + nb + seg * 8) =
                load8(smem + fl * 136 + seg * 8);
        }
    }
}

// ---------------- block-local attention ----------------
__global__ __launch_bounds__(256) void k_attn(
    const unsigned short* __restrict__ QK,     // [B*N][768]
    const unsigned short* __restrict__ Vt,     // [B][8][48][4096]
    unsigned short* __restrict__ AO)           // [B*N][384]
{
    __shared__ unsigned short ql[64][72];
    __shared__ unsigned short kl[64][72];
    __shared__ unsigned short vt[48][72];
    __shared__ float          sc[64][66];
    __shared__ unsigned short pl[64][72];

    int bx = blockIdx.x;
    int cn = bx & 63, h = (bx >> 6) & 7, b = bx >> 9;
    int n0 = cn * 64;
    int tid = threadIdx.x, wid = tid >> 6, lane = tid & 63;
    int l15 = lane & 15, quad = lane >> 4;
    int m0w = wid * 16;
    int h48 = h * 48;
    size_t b4 = (size_t)b * NN + n0;

    // stage Q,K rows (6 x 16B chunks per row per matrix)
    for (int v = tid; v < 768; v += 256) {
        int mat = v / 384;
        int idx = v - mat * 384;
        int rr = idx / 6, seg = idx - rr * 6;
        uint4 val = *reinterpret_cast<const uint4*>(QK + (b4 + rr) * 768 + mat * 384 + h48 + seg * 8);
        unsigned short* dst = mat ? &kl[rr][seg * 8] : &ql[rr][seg * 8];
        *reinterpret_cast<uint4*>(dst) = val;
    }
    // zero-pad d = 48..63
    {
        short8 z = {};
        int v = tid;
        if (v < 256) {
            int mat = v >> 7, rr = (v >> 1) & 63, half = v & 1;
            unsigned short* dst = mat ? &kl[rr][48 + half * 8] : &ql[rr][48 + half * 8];
            *reinterpret_cast<short8*>(dst) = z;
        }
    }
    // stage V^T rows (48 d-rows x 8 chunks)
    for (int v = tid; v < 384; v += 256) {
        int d = v >> 3, seg = v & 7;
        *reinterpret_cast<uint4*>(&vt[d][seg * 8]) =
            *reinterpret_cast<const uint4*>(Vt + (((size_t)(b * 8 + h) * 48 + d) << 12) + n0 + seg * 8);
    }
    __syncthreads();

    const float scale = 0.14433756729740643f;  // 48^-0.5
    #pragma unroll
    for (int t = 0; t < 4; ++t) {
        floatx4 sacc = {};
        #pragma unroll
        for (int ks = 0; ks < 2; ++ks) {
            short8 a  = load8(&ql[m0w + l15][ks * 32 + quad * 8]);
            short8 bb = load8(&kl[t * 16 + l15][ks * 32 + quad * 8]);
            sacc = __builtin_amdgcn_mfma_f32_16x16x32_bf16(a, bb, sacc, 0, 0, 0);
        }
        #pragma unroll
        for (int r = 0; r < 4; ++r)
            sc[m0w + quad * 4 + r][t * 16 + l15] = sacc[r] * scale;
    }
    __syncthreads();

    // softmax: 64 rows, wave w owns rows w*16..+16, quad owns 16 cols
    {
        int row = m0w + l15;
        int jb  = quad * 16;
        float ev[16];
        #pragma unroll
        for (int jj = 0; jj < 16; ++jj) ev[jj] = sc[row][jb + jj];
        float m = ev[0];
        #pragma unroll
        for (int jj = 1; jj < 16; ++jj) m = fmaxf(m, ev[jj]);
        m = fmaxf(m, __shfl_xor(m, 16));
        m = fmaxf(m, __shfl_xor(m, 32));
        float s = 0.f;
        #pragma unroll
        for (int jj = 0; jj < 16; ++jj) { ev[jj] = __expf(ev[jj] - m); s += ev[jj]; }
        s += __shfl_xor(s, 16);
        s += __shfl_xor(s, 32);
        float inv = 1.0f / s;
        #pragma unroll
        for (int jj = 0; jj < 16; ++jj) pl[row][jb + jj] = f32_to_bf16_bits(ev[jj] * inv);
    }
    __syncthreads();

    // PV: A = pl [q][ki], B = vt [d][ki]; O tile staged into kl (free now)
    #pragma unroll
    for (int t = 0; t < 3; ++t) {
        floatx4 oacc = {};
        #pragma unroll
        for (int ks = 0; ks < 2; ++ks) {
            short8 a  = load8(&pl[m0w + l15][ks * 32 + quad * 8]);
            short8 bb = load8(&vt[t * 16 + l15][ks * 32 + quad * 8]);
            oacc = __builtin_amdgcn_mfma_f32_16x16x32_bf16(a, bb, oacc, 0, 0, 0);
        }
        #pragma unroll
        for (int r = 0; r < 4; ++r)
            kl[m0w + quad * 4 + r][t * 16 + l15] = f32_to_bf16_bits(oacc[r]);
    }
    __syncthreads();

    for (int v = tid; v < 384; v += 256) {
        int rr = v / 6, seg = v - rr * 6;
        *reinterpret_cast<short8*>(AO + (b4 + rr) * CC + h48 + seg * 8) =
            load8(&kl[rr][seg * 8]);
    }
}

// ---------------- proj GEMM (BK=32 dbuf, seg-XOR swizzle) + bias + transpose-store f32 ----------------
__global__ __launch_bounds__(256) void k_proj(
    const unsigned short* __restrict__ A,      // AO [65536][384]
    const unsigned short* __restrict__ W,      // w2 [384][384]
    const float* __restrict__ bias,            // [384] f32
    float* __restrict__ out)                   // [B][C][N] f32
{
    __shared__ unsigned short smem[17408];     // 16 KiB staging x2 + f32 epilogue arena (33.8KB)
    float* fs = (float*)smem;                  // [64][132] f32 staging
    // XCD-aware swizzle (T1): 1536 blocks = 8 XCDs x 192 (bijective).
    int bx = blockIdx.x;
    int l  = (bx & 7) * 192 + (bx >> 3);
    int tf = l % 3, tm = l / 3;
    int m0 = tm * 128, f0 = tf * 128;
    int tid = threadIdx.x, wid = tid >> 6, lane = tid & 63;
    int l15 = lane & 15, quad = lane >> 4;
    int wm = wid & 1, wn = wid >> 1;

    const unsigned short* Ab = A + (size_t)m0 * CK;
    const unsigned short* Wb = W + (size_t)f0 * CK;

    floatx4 acc[4][4] = {};

    auto stage = [&](int kt, int buf) {
        int k0 = kt * 32;
        unsigned short* Asd = smem + buf * 8192;
        unsigned short* Wsd = Asd + 4096;
        #pragma unroll
        for (int i = 0; i < 2; ++i) {
            int c = i * 256 + tid;
            int row = c >> 2;
            int sg  = (c & 3) ^ (row & 3);
            async16(Ab + (size_t)row * CK + k0 + sg * 8, Asd + (i * 256 + wid * 64) * 8);
            async16(Wb + (size_t)row * CK + k0 + sg * 8, Wsd + (i * 256 + wid * 64) * 8);
        }
    };

    stage(0, 0);
    __syncthreads();

    int sx = (quad ^ (l15 & 3)) * 8;
    int cur = 0;
    #pragma unroll
    for (int kk = 0; kk < 12; ++kk) {
        if (kk < 11) stage(kk + 1, cur ^ 1);
        unsigned short* As = smem + cur * 8192;
        unsigned short* Ws = As + 4096;
        short8 a[4], bf[4];
        #pragma unroll
        for (int i = 0; i < 4; ++i)
            a[i] = load8(As + (wm * 64 + i * 16 + l15) * 32 + sx);
        #pragma unroll
        for (int j = 0; j < 4; ++j)
            bf[j] = load8(Ws + (wn * 64 + j * 16 + l15) * 32 + sx);
        #pragma unroll
        for (int i = 0; i < 4; ++i)
            #pragma unroll
            for (int j = 0; j < 4; ++j)
                acc[i][j] = __builtin_amdgcn_mfma_f32_16x16x32_bf16(a[i], bf[j], acc[i][j], 0, 0, 0);
        __syncthreads();
        cur ^= 1;
    }

    int b = m0 >> 12, nb = m0 & 4095;
    // two halves of 64 couts each, f32 transposed staging [cout][tok] ld 132
    #pragma unroll
    for (int hh = 0; hh < 2; ++hh) {
        if (wn == hh) {
            #pragma unroll
            for (int j = 0; j < 4; ++j) {
                float bv = bias[f0 + hh * 64 + j * 16 + l15];
                #pragma unroll
                for (int i = 0; i < 4; ++i)
                    #pragma unroll
                    for (int r = 0; r < 4; ++r)
                        fs[(j * 16 + l15) * 132 + wm * 64 + i * 16 + quad * 4 + r] =
                            acc[i][j][r] + bv;
            }
        }
        __syncthreads();
        #pragma unroll
        for (int it = 0; it < 8; ++it) {
            int c = it * 256 + tid;
            int cl = c >> 5, seg = c & 31;
            *reinterpret_cast<float4*>(
                out + (((size_t)(b * CC + f0 + hh * 64 + cl)) << 12) + nb + seg * 4) =
                *reinterpret_cast<const float4*>(fs + cl * 132 + seg * 4);
        }
        __syncthreads();
    }
}

extern "C" void kernel_launch(void* const* d_in, const int* in_sizes, int n_in,
                              void* d_out, int out_size, void* d_ws, size_t ws_size,
                              hipStream_t stream) {
    const float* x      = (const float*)d_in[0];
    const float* qkv_w  = (const float*)d_in[1];
    const float* proj_w = (const float*)d_in[2];
    const float* proj_b = (const float*)d_in[3];
    float* out = (float*)d_out;

    const size_t nX  = (size_t)16 * CC * NN;     // 25,165,824
    const size_t nW1 = (size_t)3 * CC * CC;      // 442,368
    const size_t nW2 = (size_t)CC * CC;          // 147,456

    unsigned short* xT  = (unsigned short*)d_ws;
    unsigned short* w1b = xT  + nX;
    unsigned short* w2b = w1b + nW1;
    unsigned short* QK  = w2b + nW2;             // [B*N][768]
    unsigned short* Vt  = QK  + (size_t)16 * NN * 768;
    unsigned short* AO  = Vt  + (size_t)16 * 8 * 48 * NN;

    k_tr  <<<dim3(16 * 6 * 64), dim3(256), 0, stream>>>(x, xT);
    k_cvt <<<dim3((int)(nW1 / 8 + 255) / 256), dim3(256), 0, stream>>>(qkv_w, w1b, (int)(nW1 / 8));
    k_cvt <<<dim3((int)(nW2 / 8 + 255) / 256), dim3(256), 0, stream>>>(proj_w, w2b, (int)(nW2 / 8));

    k_qkv <<<dim3(512 * 9), dim3(256), 0, stream>>>(xT, w1b, QK, Vt);
    k_attn<<<dim3(16 * 8 * 64), dim3(256), 0, stream>>>(QK, Vt, AO);
    k_proj<<<dim3(512 * 3), dim3(256), 0, stream>>>(AO, w2b, proj_b, out);
}

// Round 7
// 349.339 us; speedup vs baseline: 1.0931x; 1.0931x over previous
//
#include <hip/hip_runtime.h>
#include <stdint.h>

#define NH 8
#define HD 48
#define CC 384
#define NN 4096
#define CK 384

typedef short short8 __attribute__((ext_vector_type(8)));
typedef float floatx4 __attribute__((ext_vector_type(4)));

__device__ inline unsigned short f32_to_bf16_bits(float f) {
    uint32_t u = __builtin_bit_cast(uint32_t, f);
    u = (u + 0x7FFFu + ((u >> 16) & 1u)) >> 16;
    return (unsigned short)u;
}
__device__ inline short8 load8(const unsigned short* p) {
    return *reinterpret_cast<const short8*>(p);
}
typedef __attribute__((address_space(1))) const void gvoid_t;
typedef __attribute__((address_space(3))) void lvoid_t;
__device__ inline void async16(const unsigned short* g, unsigned short* l) {
    __builtin_amdgcn_global_load_lds((gvoid_t*)g, (lvoid_t*)l, 16, 0, 0);
}

// ---------------- weight convert f32 -> bf16 ----------------
__global__ __launch_bounds__(256) void k_cvt(
    const float* __restrict__ src, unsigned short* __restrict__ dst, int n8)
{
    int i = blockIdx.x * 256 + threadIdx.x;
    if (i >= n8) return;
    const float* s = src + (size_t)i * 8;
    unsigned short t[8];
    #pragma unroll
    for (int j = 0; j < 8; ++j) t[j] = f32_to_bf16_bits(s[j]);
    *reinterpret_cast<short8*>(dst + (size_t)i * 8) = *reinterpret_cast<short8*>(t);
}

// ---------------- x transpose: [B][C][N] f32 -> [B*N][C] bf16 ----------------
__global__ __launch_bounds__(256) void k_tr(
    const float* __restrict__ x, unsigned short* __restrict__ xT)
{
    __shared__ unsigned short tile[64][72];
    int bx = blockIdx.x;
    int nt = bx & 63; int rest = bx >> 6; int ct = rest % 6; int b = rest / 6;
    int c0 = ct * 64, n0 = nt * 64;
    int t = threadIdx.x;
    int nl = t & 63, w = t >> 6;
    const float* xb = x + (size_t)b * CC * NN;
    #pragma unroll
    for (int i = 0; i < 4; ++i) {
        int cl = w * 16 + i * 4;
        unsigned short u[4];
        #pragma unroll
        for (int j = 0; j < 4; ++j)
            u[j] = f32_to_bf16_bits(xb[(size_t)(c0 + cl + j) * NN + n0 + nl]);
        *reinterpret_cast<uint2*>(&tile[nl][cl]) = *reinterpret_cast<uint2*>(u);
    }
    __syncthreads();
    #pragma unroll
    for (int it = 0; it < 2; ++it) {
        int v = it * 256 + t;
        int row = v >> 3, seg = v & 7;
        *reinterpret_cast<short8*>(xT + ((size_t)b * NN + n0 + row) * CK + c0 + seg * 8) =
            load8(&tile[row][seg * 8]);
    }
}

// ---------------- QKV GEMM: 128x128, BK=32, 3-buffer counted-vmcnt (m218-min shape) ----
// A = xT [65536][384], W = w1 [1152][384]; out: QK [tok][768] + Vt [B][8][48][4096]
// One barrier/iter. Guarantees:
//  (a) tile kk visible at iter kk: prior iter ended vmcnt(4) [retires tile kk, FIFO] + s_barrier.
//  (b) buffer re-stage safe: reads of buf[(kk-1)%3] drained by lgkmcnt(0) BEFORE prior
//      barrier (r6 bug: reads could still be in flight when wave signaled barrier).
//  (c) sched_barrier(0) fences pin ds_read/MFMA placement around waits (rule #18).
// seg-XOR swizzle (verified r5): 4-way LDS read conflicts at BK=32.
__global__ __launch_bounds__(256) void k_qkv(
    const unsigned short* __restrict__ A,
    const unsigned short* __restrict__ W,
    unsigned short* __restrict__ QK,
    unsigned short* __restrict__ Vt)
{
    __shared__ unsigned short smem[24576];   // 3 x 8192 (A 4096 + W 4096) = 48 KiB -> 3 blk/CU
    // XCD-aware swizzle (T1): 4608 blocks = 8 XCDs x 576 (bijective).
    int bx = blockIdx.x;
    int l  = (bx & 7) * 576 + (bx >> 3);
    int tf = l % 9, tm = l / 9;
    int m0 = tm * 128, f0 = tf * 128;
    int tid = threadIdx.x, wid = tid >> 6, lane = tid & 63;
    int l15 = lane & 15, quad = lane >> 4;
    int wm = wid & 1, wn = wid >> 1;

    const unsigned short* Ab = A + (size_t)m0 * CK;
    const unsigned short* Wb = W + (size_t)f0 * CK;

    floatx4 acc[4][4] = {};

    // stage one 32-K tile pair into buffer `buf` (4 global_load_lds per wave)
    auto stage = [&](int kt, int buf) {
        int k0 = kt * 32;
        unsigned short* Asd = smem + buf * 8192;
        unsigned short* Wsd = Asd + 4096;
        #pragma unroll
        for (int i = 0; i < 2; ++i) {
            int c = i * 256 + tid;
            int row = c >> 2;
            int sg  = (c & 3) ^ (row & 3);   // inverse-permuted global seg
            async16(Ab + (size_t)row * CK + k0 + sg * 8, Asd + (i * 256 + wid * 64) * 8);
            async16(Wb + (size_t)row * CK + k0 + sg * 8, Wsd + (i * 256 + wid * 64) * 8);
        }
    };
    int sx = (quad ^ (l15 & 3)) * 8;         // swizzled ds_read seg offset (shorts)
    auto compute = [&](int buf) {
        unsigned short* As = smem + buf * 8192;
        unsigned short* Ws = As + 4096;
        short8 a[4], bf[4];
        #pragma unroll
        for (int i = 0; i < 4; ++i)
            a[i] = load8(As + (wm * 64 + i * 16 + l15) * 32 + sx);
        #pragma unroll
        for (int j = 0; j < 4; ++j)
            bf[j] = load8(Ws + (wn * 64 + j * 16 + l15) * 32 + sx);
        asm volatile("s_waitcnt lgkmcnt(0)" ::: "memory");  // reads DRAINED before barrier
        __builtin_amdgcn_sched_barrier(0);
        #pragma unroll
        for (int i = 0; i < 4; ++i)
            #pragma unroll
            for (int j = 0; j < 4; ++j)
                acc[i][j] = __builtin_amdgcn_mfma_f32_16x16x32_bf16(a[i], bf[j], acc[i][j], 0, 0, 0);
    };

    stage(0, 0);
    stage(1, 1);                              // 8 loads in flight
    asm volatile("s_waitcnt vmcnt(4)" ::: "memory");   // tile 0 landed
    __builtin_amdgcn_sched_barrier(0);
    __builtin_amdgcn_s_barrier();
    __builtin_amdgcn_sched_barrier(0);

    int cur = 0;
    for (int kk = 0; kk < 10; ++kk) {
        int nb3 = cur + 2; if (nb3 >= 3) nb3 -= 3;
        stage(kk + 2, nb3);                   // tile kk+2 in flight (overwrites buf of tile kk-1)
        compute(cur);                         // read tile kk; lgkm(0) inside
        asm volatile("s_waitcnt vmcnt(4)" ::: "memory");  // tile kk+1 retired (FIFO)
        __builtin_amdgcn_sched_barrier(0);
        __builtin_amdgcn_s_barrier();
        __builtin_amdgcn_sched_barrier(0);
        cur = cur + 1 == 3 ? 0 : cur + 1;
    }
    // kk = 10: tile 10 ready, tile 11 in flight
    compute(cur);
    asm volatile("s_waitcnt vmcnt(0)" ::: "memory");
    __builtin_amdgcn_sched_barrier(0);
    __builtin_amdgcn_s_barrier();
    __builtin_amdgcn_sched_barrier(0);
    cur = cur + 1 == 3 ? 0 : cur + 1;
    // kk = 11
    compute(cur);
    __syncthreads();                          // full drain before epilogue smem reuse

    int b = m0 >> 12, nb = m0 & 4095;
    if (tf < 6) {
        #pragma unroll
        for (int i = 0; i < 4; ++i)
            #pragma unroll
            for (int j = 0; j < 4; ++j)
                #pragma unroll
                for (int r = 0; r < 4; ++r)
                    smem[(wm * 64 + i * 16 + quad * 4 + r) * 128 + wn * 64 + j * 16 + l15] =
                        f32_to_bf16_bits(acc[i][j][r]);
        __syncthreads();
        #pragma unroll
        for (int it = 0; it < 8; ++it) {
            int c = it * 256 + tid;
            int row = c >> 4, seg = c & 15;
            *reinterpret_cast<short8*>(QK + (size_t)(m0 + row) * 768 + f0 + seg * 8) =
                load8(smem + row * 128 + seg * 8);
        }
    } else {
        #pragma unroll
        for (int i = 0; i < 4; ++i)
            #pragma unroll
            for (int j = 0; j < 4; ++j)
                #pragma unroll
                for (int r = 0; r < 4; ++r)
                    smem[(wn * 64 + j * 16 + l15) * 136 + wm * 64 + i * 16 + quad * 4 + r] =
                        f32_to_bf16_bits(acc[i][j][r]);
        __syncthreads();
        int fvb = (tf - 6) * 128;
        #pragma unroll
        for (int it = 0; it < 8; ++it) {
            int c = it * 256 + tid;
            int fl = c >> 4, seg = c & 15;
            int fv = fvb + fl;
            int h = fv / 48, d = fv - h * 48;
            *reinterpret_cast<short8*>(Vt + (((size_t)(b * 8 + h) * 48 + d) << 12) + nb + seg * 8) =
                load8(smem + fl * 136 + seg * 8);
        }
    }
}

// ---------------- block-local attention ----------------
__global__ __launch_bounds__(256) void k_attn(
    const unsigned short* __restrict__ QK,     // [B*N][768]
    const unsigned short* __restrict__ Vt,     // [B][8][48][4096]
    unsigned short* __restrict__ AO)           // [B*N][384]
{
    __shared__ unsigned short ql[64][72];
    __shared__ unsigned short kl[64][72];
    __shared__ unsigned short vt[48][72];
    __shared__ float          sc[64][66];
    __shared__ unsigned short pl[64][72];

    int bx = blockIdx.x;
    int cn = bx & 63, h = (bx >> 6) & 7, b = bx >> 9;
    int n0 = cn * 64;
    int tid = threadIdx.x, wid = tid >> 6, lane = tid & 63;
    int l15 = lane & 15, quad = lane >> 4;
    int m0w = wid * 16;
    int h48 = h * 48;
    size_t b4 = (size_t)b * NN + n0;

    // stage Q,K rows (6 x 16B chunks per row per matrix)
    for (int v = tid; v < 768; v += 256) {
        int mat = v / 384;
        int idx = v - mat * 384;
        int rr = idx / 6, seg = idx - rr * 6;
        uint4 val = *reinterpret_cast<const uint4*>(QK + (b4 + rr) * 768 + mat * 384 + h48 + seg * 8);
        unsigned short* dst = mat ? &kl[rr][seg * 8] : &ql[rr][seg * 8];
        *reinterpret_cast<uint4*>(dst) = val;
    }
    // zero-pad d = 48..63
    {
        short8 z = {};
        int v = tid;
        if (v < 256) {
            int mat = v >> 7, rr = (v >> 1) & 63, half = v & 1;
            unsigned short* dst = mat ? &kl[rr][48 + half * 8] : &ql[rr][48 + half * 8];
            *reinterpret_cast<short8*>(dst) = z;
        }
    }
    // stage V^T rows (48 d-rows x 8 chunks)
    for (int v = tid; v < 384; v += 256) {
        int d = v >> 3, seg = v & 7;
        *reinterpret_cast<uint4*>(&vt[d][seg * 8]) =
            *reinterpret_cast<const uint4*>(Vt + (((size_t)(b * 8 + h) * 48 + d) << 12) + n0 + seg * 8);
    }
    __syncthreads();

    const float scale = 0.14433756729740643f;  // 48^-0.5
    #pragma unroll
    for (int t = 0; t < 4; ++t) {
        floatx4 sacc = {};
        #pragma unroll
        for (int ks = 0; ks < 2; ++ks) {
            short8 a  = load8(&ql[m0w + l15][ks * 32 + quad * 8]);
            short8 bb = load8(&kl[t * 16 + l15][ks * 32 + quad * 8]);
            sacc = __builtin_amdgcn_mfma_f32_16x16x32_bf16(a, bb, sacc, 0, 0, 0);
        }
        #pragma unroll
        for (int r = 0; r < 4; ++r)
            sc[m0w + quad * 4 + r][t * 16 + l15] = sacc[r] * scale;
    }
    __syncthreads();

    // softmax: 64 rows, wave w owns rows w*16..+16, quad owns 16 cols
    {
        int row = m0w + l15;
        int jb  = quad * 16;
        float ev[16];
        #pragma unroll
        for (int jj = 0; jj < 16; ++jj) ev[jj] = sc[row][jb + jj];
        float m = ev[0];
        #pragma unroll
        for (int jj = 1; jj < 16; ++jj) m = fmaxf(m, ev[jj]);
        m = fmaxf(m, __shfl_xor(m, 16));
        m = fmaxf(m, __shfl_xor(m, 32));
        float s = 0.f;
        #pragma unroll
        for (int jj = 0; jj < 16; ++jj) { ev[jj] = __expf(ev[jj] - m); s += ev[jj]; }
        s += __shfl_xor(s, 16);
        s += __shfl_xor(s, 32);
        float inv = 1.0f / s;
        #pragma unroll
        for (int jj = 0; jj < 16; ++jj) pl[row][jb + jj] = f32_to_bf16_bits(ev[jj] * inv);
    }
    __syncthreads();

    // PV: A = pl [q][ki], B = vt [d][ki]; O tile staged into kl (free now)
    #pragma unroll
    for (int t = 0; t < 3; ++t) {
        floatx4 oacc = {};
        #pragma unroll
        for (int ks = 0; ks < 2; ++ks) {
            short8 a  = load8(&pl[m0w + l15][ks * 32 + quad * 8]);
            short8 bb = load8(&vt[t * 16 + l15][ks * 32 + quad * 8]);
            oacc = __builtin_amdgcn_mfma_f32_16x16x32_bf16(a, bb, oacc, 0, 0, 0);
        }
        #pragma unroll
        for (int r = 0; r < 4; ++r)
            kl[m0w + quad * 4 + r][t * 16 + l15] = f32_to_bf16_bits(oacc[r]);
    }
    __syncthreads();

    for (int v = tid; v < 384; v += 256) {
        int rr = v / 6, seg = v - rr * 6;
        *reinterpret_cast<short8*>(AO + (b4 + rr) * CC + h48 + seg * 8) =
            load8(&kl[rr][seg * 8]);
    }
}

// ---------------- proj GEMM: BK=32, 3-buffer counted-vmcnt + bias + transpose f32 ----------------
__global__ __launch_bounds__(256) void k_proj(
    const unsigned short* __restrict__ A,      // AO [65536][384]
    const unsigned short* __restrict__ W,      // w2 [384][384]
    const float* __restrict__ bias,            // [384] f32
    float* __restrict__ out)                   // [B][C][N] f32
{
    __shared__ unsigned short smem[24576];     // 48 KiB: 3-buffer staging + f32 epilogue arena
    float* fs = (float*)smem;                  // [64][132] f32 staging (33792 B < 49152)
    // XCD-aware swizzle (T1): 1536 blocks = 8 XCDs x 192 (bijective).
    int bx = blockIdx.x;
    int l  = (bx & 7) * 192 + (bx >> 3);
    int tf = l % 3, tm = l / 3;
    int m0 = tm * 128, f0 = tf * 128;
    int tid = threadIdx.x, wid = tid >> 6, lane = tid & 63;
    int l15 = lane & 15, quad = lane >> 4;
    int wm = wid & 1, wn = wid >> 1;

    const unsigned short* Ab = A + (size_t)m0 * CK;
    const unsigned short* Wb = W + (size_t)f0 * CK;

    floatx4 acc[4][4] = {};

    auto stage = [&](int kt, int buf) {
        int k0 = kt * 32;
        unsigned short* Asd = smem + buf * 8192;
        unsigned short* Wsd = Asd + 4096;
        #pragma unroll
        for (int i = 0; i < 2; ++i) {
            int c = i * 256 + tid;
            int row = c >> 2;
            int sg  = (c & 3) ^ (row & 3);
            async16(Ab + (size_t)row * CK + k0 + sg * 8, Asd + (i * 256 + wid * 64) * 8);
            async16(Wb + (size_t)row * CK + k0 + sg * 8, Wsd + (i * 256 + wid * 64) * 8);
        }
    };
    int sx = (quad ^ (l15 & 3)) * 8;
    auto compute = [&](int buf) {
        unsigned short* As = smem + buf * 8192;
        unsigned short* Ws = As + 4096;
        short8 a[4], bf[4];
        #pragma unroll
        for (int i = 0; i < 4; ++i)
            a[i] = load8(As + (wm * 64 + i * 16 + l15) * 32 + sx);
        #pragma unroll
        for (int j = 0; j < 4; ++j)
            bf[j] = load8(Ws + (wn * 64 + j * 16 + l15) * 32 + sx);
        asm volatile("s_waitcnt lgkmcnt(0)" ::: "memory");
        __builtin_amdgcn_sched_barrier(0);
        #pragma unroll
        for (int i = 0; i < 4; ++i)
            #pragma unroll
            for (int j = 0; j < 4; ++j)
                acc[i][j] = __builtin_amdgcn_mfma_f32_16x16x32_bf16(a[i], bf[j], acc[i][j], 0, 0, 0);
    };

    stage(0, 0);
    stage(1, 1);
    asm volatile("s_waitcnt vmcnt(4)" ::: "memory");
    __builtin_amdgcn_sched_barrier(0);
    __builtin_amdgcn_s_barrier();
    __builtin_amdgcn_sched_barrier(0);

    int cur = 0;
    for (int kk = 0; kk < 10; ++kk) {
        int nb3 = cur + 2; if (nb3 >= 3) nb3 -= 3;
        stage(kk + 2, nb3);
        compute(cur);
        asm volatile("s_waitcnt vmcnt(4)" ::: "memory");
        __builtin_amdgcn_sched_barrier(0);
        __builtin_amdgcn_s_barrier();
        __builtin_amdgcn_sched_barrier(0);
        cur = cur + 1 == 3 ? 0 : cur + 1;
    }
    compute(cur);
    asm volatile("s_waitcnt vmcnt(0)" ::: "memory");
    __builtin_amdgcn_sched_barrier(0);
    __builtin_amdgcn_s_barrier();
    __builtin_amdgcn_sched_barrier(0);
    cur = cur + 1 == 3 ? 0 : cur + 1;
    compute(cur);
    __syncthreads();

    int b = m0 >> 12, nb = m0 & 4095;
    // two halves of 64 couts each, f32 transposed staging [cout][tok] ld 132
    #pragma unroll
    for (int hh = 0; hh < 2; ++hh) {
        if (wn == hh) {
            #pragma unroll
            for (int j = 0; j < 4; ++j) {
                float bv = bias[f0 + hh * 64 + j * 16 + l15];
                #pragma unroll
                for (int i = 0; i < 4; ++i)
                    #pragma unroll
                    for (int r = 0; r < 4; ++r)
                        fs[(j * 16 + l15) * 132 + wm * 64 + i * 16 + quad * 4 + r] =
                            acc[i][j][r] + bv;
            }
        }
        __syncthreads();
        #pragma unroll
        for (int it = 0; it < 8; ++it) {
            int c = it * 256 + tid;
            int cl = c >> 5, seg = c & 31;
            *reinterpret_cast<float4*>(
                out + (((size_t)(b * CC + f0 + hh * 64 + cl)) << 12) + nb + seg * 4) =
                *reinterpret_cast<const float4*>(fs + cl * 132 + seg * 4);
        }
        __syncthreads();
    }
}

extern "C" void kernel_launch(void* const* d_in, const int* in_sizes, int n_in,
                              void* d_out, int out_size, void* d_ws, size_t ws_size,
                              hipStream_t stream) {
    const float* x      = (const float*)d_in[0];
    const float* qkv_w  = (const float*)d_in[1];
    const float* proj_w = (const float*)d_in[2];
    const float* proj_b = (const float*)d_in[3];
    float* out = (float*)d_out;

    const size_t nX  = (size_t)16 * CC * NN;     // 25,165,824
    const size_t nW1 = (size_t)3 * CC * CC;      // 442,368
    const size_t nW2 = (size_t)CC * CC;          // 147,456

    unsigned short* xT  = (unsigned short*)d_ws;
    unsigned short* w1b = xT  + nX;
    unsigned short* w2b = w1b + nW1;
    unsigned short* QK  = w2b + nW2;             // [B*N][768]
    unsigned short* Vt  = QK  + (size_t)16 * NN * 768;
    unsigned short* AO  = Vt  + (size_t)16 * 8 * 48 * NN;

    k_tr  <<<dim3(16 * 6 * 64), dim3(256), 0, stream>>>(x, xT);
    k_cvt <<<dim3((int)(nW1 / 8 + 255) / 256), dim3(256), 0, stream>>>(qkv_w, w1b, (int)(nW1 / 8));
    k_cvt <<<dim3((int)(nW2 / 8 + 255) / 256), dim3(256), 0, stream>>>(proj_w, w2b, (int)(nW2 / 8));

    k_qkv <<<dim3(512 * 9), dim3(256), 0, stream>>>(xT, w1b, QK, Vt);
    k_attn<<<dim3(16 * 8 * 64), dim3(256), 0, stream>>>(QK, Vt, AO);
    k_proj<<<dim3(512 * 3), dim3(256), 0, stream>>>(AO, w2b, proj_b, out);
}